// Round 16
// baseline (838.264 us; speedup 1.0000x reference)
//
#include <hip/hip_runtime.h>
#include <hip/hip_bf16.h>
#include <stdint.h>

#define DEV static __device__ __forceinline__

typedef __bf16 bf16_t;
typedef __bf16 bf16x8 __attribute__((ext_vector_type(8)));
typedef __bf16 bf16x4 __attribute__((ext_vector_type(4)));
typedef __bf16 bf16x2 __attribute__((ext_vector_type(2)));
typedef float  f32x4  __attribute__((ext_vector_type(4)));

// H=32 q heads, KV=8 kv heads, D=128, HID=4096, S=4, L=1024, N=4096

DEV void gload_lds16(const void* g, void* l) {
  __builtin_amdgcn_global_load_lds(
      (__attribute__((address_space(1))) void*)(uintptr_t)(g),
      (__attribute__((address_space(3))) void*)(uintptr_t)(l),
      16, 0, 0);
}

#define BARRIER() asm volatile("s_barrier" ::: "memory")
#define MFMA16(a, b, c) __builtin_amdgcn_mfma_f32_16x16x32_bf16((a), (b), (c), 0, 0, 0)

// ---------------- unified pack/convert kernel (16B stores) ----------------
DEV void pack_pair_chunk8(const float* __restrict__ A, const float* __restrict__ B,
                          bf16_t* __restrict__ dst, size_t i) {
  size_t r = i >> 9, c = i & 511;
  const float4* pa = (const float4*)A + r * 1024 + c * 2;
  const float4* pb = (const float4*)B + r * 1024 + c * 2;
  float4 a0 = pa[0], a1 = pa[1];
  float4 b0 = pb[0], b1 = pb[1];
  bf16x8 oa = {(bf16_t)a0.x, (bf16_t)a0.y, (bf16_t)a0.z, (bf16_t)a0.w,
               (bf16_t)a1.x, (bf16_t)a1.y, (bf16_t)a1.z, (bf16_t)a1.w};
  bf16x8 ob = {(bf16_t)b0.x, (bf16_t)b0.y, (bf16_t)b0.z, (bf16_t)b0.w,
               (bf16_t)b1.x, (bf16_t)b1.y, (bf16_t)b1.z, (bf16_t)b1.w};
  ((bf16x8*)dst)[r * 1024 + c]       = oa;
  ((bf16x8*)dst)[r * 1024 + 512 + c] = ob;
}

__global__ void k_pack_all(const float* __restrict__ hidden, const float* __restrict__ mu,
                           const float* __restrict__ Wq, const float* __restrict__ Wmq,
                           const float* __restrict__ Wk, const float* __restrict__ Wmk,
                           const float* __restrict__ Wv, const float* __restrict__ Wmv,
                           const float* __restrict__ Wo,
                           bf16_t* __restrict__ Xb, bf16_t* __restrict__ Wqkv,
                           bf16_t* __restrict__ Wob) {
  const size_t t0 = 2097152, t1 = 4194304, t2 = 4718592, t3 = 5242880, t4 = 7340032;
  size_t stride = (size_t)gridDim.x * blockDim.x;
  for (size_t i = (size_t)blockIdx.x * blockDim.x + threadIdx.x; i < t4; i += stride) {
    if (i < t0) {
      pack_pair_chunk8(hidden, mu, Xb, i);
    } else if (i < t1) {
      pack_pair_chunk8(Wq, Wmq, Wqkv, i - t0);
    } else if (i < t2) {
      pack_pair_chunk8(Wk, Wmk, Wqkv + (size_t)4096 * 8192, i - t1);
    } else if (i < t3) {
      pack_pair_chunk8(Wv, Wmv, Wqkv + (size_t)5120 * 8192, i - t2);
    } else {
      size_t j = i - t3;
      const float4* p = (const float4*)Wo + j * 2;
      float4 v0 = p[0], v1 = p[1];
      bf16x8 o = {(bf16_t)v0.x, (bf16_t)v0.y, (bf16_t)v0.z, (bf16_t)v0.w,
                  (bf16_t)v1.x, (bf16_t)v1.y, (bf16_t)v1.z, (bf16_t)v1.w};
      ((bf16x8*)Wob)[j] = o;
    }
  }
}

// ---------------- 256x256 bf16 GEMM, 1 barrier/tile (wave-drift overlap) ----------------
// 512 threads = 8 waves (2M x 4N), BK=64. LDS 2 x 64KB contiguous tiles (A 32KB + B 32KB),
// 16B-chunk XOR swizzle (chunk ^= row&7; inverse on global source, applied on ds_read).
// Per tile, ONE barrier-free region: RD A-h0+B (16) -> STG next tile (8 gloads) ->
// MM(0,*) -> RD A-h1 (8) -> MM(1,*) -> vmcnt(0) -> barrier. No interior barriers: the
// 2 waves/SIMD drift, so one wave's LDS reads overlap its sibling's MFMAs (the R5..R14
// barrier-lockstep serialized reads[2300cyc] + MFMA[2484cyc]; target max() instead).
// Hazards: STG targets buf^1 (last read in tile t-1, closed by its barrier); this tile's
// data staged in t-1, drained by t-1's vmcnt(0).
template<typename CT, int NSPLIT>
__global__ __launch_bounds__(512, 2) void k_gemm256(
    const bf16_t* __restrict__ A, const bf16_t* __restrict__ B,
    CT* __restrict__ C, int M, int N, int Kfull) {
  __shared__ __align__(16) char lds[131072];
  const int tid = threadIdx.x, lane = tid & 63, wid = tid >> 6;
  const int l15 = lane & 15, lhi = lane >> 4;
  const int wr = wid >> 2, wc = wid & 3;
  const int bid = blockIdx.x, nwg = gridDim.x;
  const int cpx = nwg >> 3;
  const int swz = (bid & 7) * cpx + (bid >> 3);
  const int nbm = M >> 8;
  const int tiles = nbm * (N >> 8);
  const int ks = (NSPLIT > 1) ? (swz / tiles) : 0;
  const int t0i = (NSPLIT > 1) ? (swz % tiles) : swz;
  const int bm = t0i % nbm, bn = t0i / nbm;   // bm-fast
  const int Kloop = Kfull / NSPLIT;
  const int nkt = Kloop >> 6;

  const size_t rowK = (size_t)Kfull * 2;
  const size_t kbase = (size_t)ks * Kloop * 2;
  // staging: thread covers row srow+64j, chunk tid&7 (swizzled source)
  const int srow = tid >> 3;
  const int scs = (tid & 7) ^ (srow & 7);
  const char* sA = (const char*)A + ((size_t)bm * 256 + srow) * rowK + kbase + scs * 16;
  const char* sB = (const char*)B + ((size_t)bn * 256 + srow) * rowK + kbase + scs * 16;
  const size_t r64 = (size_t)64 * rowK;

#define STG(bufp, kb) do { _Pragma("unroll") \
    for (int j = 0; j < 4; ++j) { \
      gload_lds16(sA + (size_t)j * r64 + (kb), (bufp) + j * 8192 + tid * 16); \
      gload_lds16(sB + (size_t)j * r64 + (kb), (bufp) + 32768 + j * 8192 + tid * 16); \
    } } while (0)

  f32x4 acc[8][4] = {};
  bf16x8 a[4][2], b[4][2];
  const int xr = l15 & 7;
  const int ck0 = ((lhi ^ xr)) * 16;        // byte offset of ks=0 chunk
  const int ck1 = (((4 + lhi) ^ xr)) * 16;  // ks=1 chunk

  // fragment row bases (bytes): A row = wr*128 + mi*16 + l15; B row = wc*64 + n*16 + l15
#define RD_A(bufp, rb) do { _Pragma("unroll") \
    for (int mi = 0; mi < 4; ++mi) { \
      const char* rp = (bufp) + (wr * 128 + (rb) + mi * 16 + l15) * 128; \
      a[mi][0] = *(const bf16x8*)(rp + ck0); \
      a[mi][1] = *(const bf16x8*)(rp + ck1); } } while (0)
#define RD_B2(bufp, n0) do { _Pragma("unroll") \
    for (int n = (n0); n < (n0) + 2; ++n) { \
      const char* rp = (bufp) + 32768 + (wc * 64 + n * 16 + l15) * 128; \
      b[n][0] = *(const bf16x8*)(rp + ck0); \
      b[n][1] = *(const bf16x8*)(rp + ck1); } } while (0)
#define MM(qm, qn) do { _Pragma("unroll") \
    for (int mi = 0; mi < 4; ++mi) { _Pragma("unroll") \
      for (int ni = 0; ni < 2; ++ni) { \
        f32x4 t_ = acc[(qm) * 4 + mi][(qn) * 2 + ni]; \
        t_ = MFMA16(a[mi][0], b[(qn) * 2 + ni][0], t_); \
        t_ = MFMA16(a[mi][1], b[(qn) * 2 + ni][1], t_); \
        acc[(qm) * 4 + mi][(qn) * 2 + ni] = t_; } } } while (0)
#define PRIO_MM(qm, qn) do { __builtin_amdgcn_s_setprio(1); MM(qm, qn); \
    __builtin_amdgcn_s_setprio(0); } while (0)

  // prologue: stage tile 0 into buf0
  STG(lds, 0);
  asm volatile("s_waitcnt vmcnt(0)" ::: "memory");
  BARRIER();

  int bufo = 0;
  for (int t = 0; t < nkt; ++t) {
    const char* bp = lds + bufo;
    RD_A(bp, 0);
    RD_B2(bp, 0);
    RD_B2(bp, 2);
    if (t + 1 < nkt) STG(lds + (bufo ^ 65536), (size_t)(t + 1) * 128);
    PRIO_MM(0, 0);
    PRIO_MM(0, 1);
    RD_A(bp, 64);
    PRIO_MM(1, 0);
    PRIO_MM(1, 1);
    asm volatile("s_waitcnt vmcnt(0)" ::: "memory");
    BARRIER();
    bufo ^= 65536;
  }

  // epilogue: C/D layout col=lane&15, row=4*(lane>>4)+reg
  CT* Cp = C + (size_t)ks * M * N;
#pragma unroll
  for (int m = 0; m < 8; ++m) {
    const int row0 = bm * 256 + wr * 128 + m * 16 + 4 * lhi;
#pragma unroll
    for (int n = 0; n < 4; ++n) {
      const int col = bn * 256 + wc * 64 + n * 16 + l15;
#pragma unroll
      for (int i = 0; i < 4; ++i)
        Cp[(size_t)(row0 + i) * N + col] = (CT)acc[m][n][i];
    }
  }
#undef STG
#undef RD_A
#undef RD_B2
#undef MM
#undef PRIO_MM
}

// ---------------- RMSNorm + RoPE (vectorized bf16x2, half-wave per slot) ----------------
__global__ __launch_bounds__(256) void k_norm_rope(
    const bf16_t* __restrict__ qkvA, const bf16_t* __restrict__ qkvB,
    const int* __restrict__ pos,
    const float* __restrict__ qw, const float* __restrict__ kw,
    bf16_t* __restrict__ Q, bf16_t* __restrict__ Kk, bf16_t* __restrict__ V) {
  const int lane = threadIdx.x & 63, wid = threadIdx.x >> 6;
  const int l32 = lane & 31;
  const int gslot = blockIdx.x * 8 + wid * 2 + (lane >> 5);
  const int n = gslot / 48, slot = gslot % 48;
  const int d0 = 2 * l32;
  const bf16_t* rowA = qkvA + (size_t)n * 6144;
  const bf16_t* rowB = qkvB + (size_t)n * 6144;

  if (slot >= 40) {
    const int h2 = slot - 40;
    const int c = 5120 + h2 * 128 + d0;
    bf16x2 aL = *(const bf16x2*)(rowA + c),     bL = *(const bf16x2*)(rowB + c);
    bf16x2 aH = *(const bf16x2*)(rowA + c + 64), bH = *(const bf16x2*)(rowB + c + 64);
    bf16x2 oL = {(bf16_t)((float)aL[0] + (float)bL[0]), (bf16_t)((float)aL[1] + (float)bL[1])};
    bf16x2 oH = {(bf16_t)((float)aH[0] + (float)bH[0]), (bf16_t)((float)aH[1] + (float)bH[1])};
    bf16_t* dst = V + ((size_t)n * 8 + h2) * 128;
    *(bf16x2*)(dst + d0) = oL;
    *(bf16x2*)(dst + d0 + 64) = oH;
    return;
  }
  const bool isq = slot < 32;
  const int h = isq ? slot : slot - 32;
  const int c = (isq ? h * 128 : 4096 + h * 128) + d0;
  bf16x2 aL = *(const bf16x2*)(rowA + c),      bL = *(const bf16x2*)(rowB + c);
  bf16x2 aH = *(const bf16x2*)(rowA + c + 64), bH = *(const bf16x2*)(rowB + c + 64);
  float xL0 = (float)aL[0] + (float)bL[0], xL1 = (float)aL[1] + (float)bL[1];
  float xH0 = (float)aH[0] + (float)bH[0], xH1 = (float)aH[1] + (float)bH[1];
  float ss = xL0 * xL0 + xL1 * xL1 + xH0 * xH0 + xH1 * xH1;
#pragma unroll
  for (int m = 16; m; m >>= 1) ss += __shfl_xor(ss, m, 64);
  const float inv = rsqrtf(ss * (1.0f / 128.0f) + 1e-6f);
  const float* wgt = isq ? qw : kw;
  float yL0 = xL0 * inv * wgt[d0],      yL1 = xL1 * inv * wgt[d0 + 1];
  float yH0 = xH0 * inv * wgt[d0 + 64], yH1 = xH1 * inv * wgt[d0 + 65];
  const float p = (float)pos[n];
  const float ang0 = p * expf((float)d0 * -0.14391156608f);
  const float ang1 = p * expf((float)(d0 + 1) * -0.14391156608f);
  float s0, c0f, s1, c1f;
  sincosf(ang0, &s0, &c0f);
  sincosf(ang1, &s1, &c1f);
  bf16x2 oL = {(bf16_t)(yL0 * c0f - yH0 * s0), (bf16_t)(yL1 * c1f - yH1 * s1)};
  bf16x2 oH = {(bf16_t)(yH0 * c0f + yL0 * s0), (bf16_t)(yH1 * c1f + yL1 * s1)};
  bf16_t* dst = isq ? (Q + ((size_t)n * 32 + h) * 128) : (Kk + ((size_t)n * 8 + h) * 128);
  *(bf16x2*)(dst + d0) = oL;
  *(bf16x2*)(dst + d0 + 64) = oH;
}

// ---------------- V transpose: V[4096][8][128] -> Vt[s][kvh][d][1024] ----------------
__global__ __launch_bounds__(256) void k_vt(const bf16_t* __restrict__ V,
                                            bf16_t* __restrict__ Vt) {
  __shared__ bf16_t T[64][136];
  const int blk = blockIdx.x;
  const int tt = blk & 15, kvh = (blk >> 4) & 7, s = blk >> 7;
  const int tok0 = tt * 64;
  const int tid = threadIdx.x;
#pragma unroll
  for (int k = 0; k < 4; ++k) {
    const int item = tid + k * 256;
    const int tok = item >> 4, d0 = (item & 15) * 8;
    bf16x8 v = *(const bf16x8*)(V + ((size_t)(s * 1024 + tok0 + tok) * 8 + kvh) * 128 + d0);
    *(bf16x8*)(&T[tok][d0]) = v;
  }
  __syncthreads();
#pragma unroll
  for (int k = 0; k < 4; ++k) {
    const int item = tid + k * 256;
    const int d = item & 127, oct = item >> 7;
    bf16x8 o;
#pragma unroll
    for (int j = 0; j < 8; ++j) o[j] = T[oct * 8 + j][d];
    *(bf16x8*)(Vt + ((size_t)((s * 8 + kvh) * 128 + d)) * 1024 + tok0 + oct * 8) = o;
  }
}

// ---------------- causal GQA flash attention ----------------
__global__ __launch_bounds__(256, 2) void k_attn(
    const bf16_t* __restrict__ Q, const bf16_t* __restrict__ Kk,
    const bf16_t* __restrict__ Vt, bf16_t* __restrict__ O) {
  __shared__ __align__(16) bf16_t Ks[2][64 * 128];
  __shared__ __align__(16) bf16_t Ps[4][32 * 72];
  const int b = blockIdx.x;
  const int x = b & 7, y = b >> 3;
  const int h = x * 4 + ((y >> 3) & 3);
  const int qb = 7 - (y & 7);
  const int s = y >> 5;
  const int kvh = h >> 2;
  const int tid = threadIdx.x, lane = tid & 63, wid = tid >> 6;
  const int l15 = lane & 15, lhi = lane >> 4;

  bf16x8 qf[2][4];
  {
    const int qrow = qb * 128 + wid * 32;
#pragma unroll
    for (int mt = 0; mt < 2; mt++) {
      const size_t base = ((size_t)(s * 1024 + qrow + mt * 16 + l15) * 32 + h) * 128;
#pragma unroll
      for (int kc = 0; kc < 4; kc++)
        qf[mt][kc] = *(const bf16x8*)(Q + base + kc * 32 + 8 * lhi);
    }
  }
  const bf16_t* Vtb = Vt + (size_t)((s * 8 + kvh) * 128) * 1024;

  f32x4 of[2][8] = {};
  float mx[2][4], li[2][4];
#pragma unroll
  for (int mt = 0; mt < 2; mt++)
#pragma unroll
    for (int i = 0; i < 4; i++) { mx[mt][i] = -1e30f; li[mt][i] = 0.f; }

  const int ktiles = (qb + 1) * 2;

  const int so = wid * 4096;
#define STAGE_K(kt_, buf_) do { _Pragma("unroll") \
    for (int c = 0; c < 4; ++c) { \
      const int o = so + c * 1024 + lane * 16; \
      const int krow = o >> 8; \
      const int cs = ((o >> 4) & 15) ^ (krow & 7); \
      const char* src = (const char*)(Kk + \
          ((size_t)(s * 1024 + (kt_) * 64 + krow) * 8 + kvh) * 128) + cs * 16; \
      gload_lds16(src, (char*)&Ks[buf_][0] + so + c * 1024); \
    } } while (0)

  STAGE_K(0, 0);
  asm volatile("s_waitcnt vmcnt(0)" ::: "memory");
  BARRIER();

  for (int kt = 0; kt < ktiles; kt++) {
    const int kv0 = kt * 64;
    const int buf = kt & 1;
    if (kt + 1 < ktiles) STAGE_K(kt + 1, buf ^ 1);

    f32x4 sf[2][4] = {};
#pragma unroll
    for (int kc = 0; kc < 4; kc++) {
      bf16x8 kf[4];
#pragma unroll
      for (int n = 0; n < 4; n++) {
        const int krow = n * 16 + l15;
        const int ci = (kc * 4 + lhi) ^ (krow & 7);
        kf[n] = *(const bf16x8*)(&Ks[buf][0] + krow * 128 + ci * 8);
      }
#pragma unroll
      for (int mt = 0; mt < 2; mt++)
#pragma unroll
        for (int n = 0; n < 4; n++)
          sf[mt][n] = MFMA16(qf[mt][kc], kf[n], sf[mt][n]);
    }

    const bool masked = (kt >= 2 * qb);
    const float scale = 0.08838834764831845f;
    float pv[2][4][4];
#pragma unroll
    for (int mt = 0; mt < 2; mt++) {
#pragma unroll
      for (int i = 0; i < 4; i++) {
        float rm = -1e30f;
#pragma unroll
        for (int n = 0; n < 4; n++) {
          float sv = sf[mt][n][i] * scale;
          if (masked) {
            const int kvg = kv0 + n * 16 + l15;
            const int qg = qb * 128 + wid * 32 + mt * 16 + 4 * lhi + i;
            if (kvg > qg) sv = -1e30f;
          }
          pv[mt][n][i] = sv;
          rm = fmaxf(rm, sv);
        }
#pragma unroll
        for (int mm = 1; mm < 16; mm <<= 1) rm = fmaxf(rm, __shfl_xor(rm, mm, 64));
        const float nm = fmaxf(mx[mt][i], rm);
        float ts = 0.f;
#pragma unroll
        for (int n = 0; n < 4; n++) {
          float e = __expf(pv[mt][n][i] - nm);
          pv[mt][n][i] = e;
          ts += e;
        }
#pragma unroll
        for (int mm = 1; mm < 16; mm <<= 1) ts += __shfl_xor(ts, mm, 64);
        const float al = __expf(mx[mt][i] - nm);
        li[mt][i] = li[mt][i] * al + ts;
        mx[mt][i] = nm;
#pragma unroll
        for (int n = 0; n < 8; n++) of[mt][n][i] *= al;
      }
    }

    bf16_t* myP = &Ps[wid][0];
#pragma unroll
    for (int mt = 0; mt < 2; mt++)
#pragma unroll
      for (int n = 0; n < 4; n++)
#pragma unroll
        for (int i = 0; i < 4; i++)
          myP[(mt * 16 + 4 * lhi + i) * 72 + n * 16 + l15] = (bf16_t)pv[mt][n][i];

#pragma unroll
    for (int kc = 0; kc < 2; kc++) {
      bf16x8 pf[2];
#pragma unroll
      for (int mt = 0; mt < 2; mt++)
        pf[mt] = *(const bf16x8*)(myP + (mt * 16 + l15) * 72 + kc * 32 + 8 * lhi);
#pragma unroll
      for (int n = 0; n < 8; n++) {
        const int d = n * 16 + l15;
        bf16x8 vf = *(const bf16x8*)(Vtb + (size_t)d * 1024 + kv0 + kc * 32 + 8 * lhi);
#pragma unroll
        for (int mt = 0; mt < 2; mt++)
          of[mt][n] = MFMA16(pf[mt], vf, of[mt][n]);
      }
    }

    if (kt + 1 < ktiles) {
      asm volatile("s_waitcnt vmcnt(0)" ::: "memory");
      BARRIER();
    }
  }
#undef STAGE_K

#pragma unroll
  for (int mt = 0; mt < 2; mt++) {
#pragma unroll
    for (int i = 0; i < 4; i++) {
      const float invl = 1.0f / li[mt][i];
      const int tokrow = qb * 128 + wid * 32 + mt * 16 + 4 * lhi + i;
      bf16_t* dst = O + (size_t)(s * 1024 + tokrow) * 4096 + h * 128;
#pragma unroll
      for (int n = 0; n < 8; n++)
        dst[n * 16 + l15] = (bf16_t)(of[mt][n][i] * invl);
    }
  }
}

// ---------------- launch ----------------
extern "C" void kernel_launch(void* const* d_in, const int* in_sizes, int n_in,
                              void* d_out, int out_size, void* d_ws, size_t ws_size,
                              hipStream_t stream) {
  const float* hidden = (const float*)d_in[0];
  const float* mu     = (const float*)d_in[1];
  const int*   pos    = (const int*)d_in[2];
  const float* Wq  = (const float*)d_in[3];
  const float* Wk  = (const float*)d_in[4];
  const float* Wv  = (const float*)d_in[5];
  const float* Wo  = (const float*)d_in[6];
  const float* Wmq = (const float*)d_in[7];
  const float* Wmk = (const float*)d_in[8];
  const float* Wmv = (const float*)d_in[9];
  const float* qw  = (const float*)d_in[10];
  const float* kw  = (const float*)d_in[11];
  float* out = (float*)d_out;
  char* ws = (char*)d_ws;

  if (ws_size < 301989888u) return;  // need 288 MiB

  bf16_t* Wqkv = (bf16_t*)(ws);                    // [6144][8192] bf16   0..96MiB
  bf16_t* Wob  = (bf16_t*)(ws + 100663296);        // [4096][4096] bf16   96..128MiB
  bf16_t* Xb   = (bf16_t*)(ws + 134217728);        // [4096][8192] bf16   128..192MiB
  bf16_t* Qb   = (bf16_t*)(ws + 134217728);        // aliases Xb (dead after GEMM1) 32MiB
  bf16_t* Kb   = (bf16_t*)(ws + 167772160);        // 8MiB
  bf16_t* Vb   = (bf16_t*)(ws + 176160768);        // 8MiB
  bf16_t* VtG  = (bf16_t*)(ws + 184549376);        // transposed V, 8MiB
  bf16_t* qkvA = (bf16_t*)(ws + 201326592);        // [4096][6144] bf16 partial ks=0 (48MiB)
  bf16_t* qkvB = (bf16_t*)(ws + 251658240);        // partial ks=1 (48MiB)
  bf16_t* Ob   = (bf16_t*)(ws + 201326592);        // aliases qkvA (dead after norm/rope) 32MiB

  k_pack_all<<<2048, 256, 0, stream>>>(hidden, mu, Wq, Wmq, Wk, Wmk, Wv, Wmv, Wo,
                                       Xb, Wqkv, Wob);
  k_gemm256<bf16_t, 2><<<768, 512, 0, stream>>>(Xb, Wqkv, qkvA, 4096, 6144, 8192);
  k_norm_rope<<<24576, 256, 0, stream>>>(qkvA, qkvB, pos, qw, kw, Qb, Kb, Vb);
  k_vt<<<512, 256, 0, stream>>>(Vb, VtG);
  k_attn<<<1024, 256, 0, stream>>>(Qb, Kb, VtG, Ob);
  k_gemm256<float, 1><<<256, 512, 0, stream>>>(Ob, Wob, out, 4096, 4096, 4096);
}

// Round 17
// 753.798 us; speedup vs baseline: 1.1121x; 1.1121x over previous
//
#include <hip/hip_runtime.h>
#include <hip/hip_bf16.h>
#include <stdint.h>

#define DEV static __device__ __forceinline__

typedef __bf16 bf16_t;
typedef __bf16 bf16x8 __attribute__((ext_vector_type(8)));
typedef __bf16 bf16x4 __attribute__((ext_vector_type(4)));
typedef __bf16 bf16x2 __attribute__((ext_vector_type(2)));
typedef float  f32x4  __attribute__((ext_vector_type(4)));

// H=32 q heads, KV=8 kv heads, D=128, HID=4096, S=4, L=1024, N=4096

DEV void gload_lds16(const void* g, void* l) {
  __builtin_amdgcn_global_load_lds(
      (__attribute__((address_space(1))) void*)(uintptr_t)(g),
      (__attribute__((address_space(3))) void*)(uintptr_t)(l),
      16, 0, 0);
}

#define BARRIER() asm volatile("s_barrier" ::: "memory")
#define MFMA16(a, b, c) __builtin_amdgcn_mfma_f32_16x16x32_bf16((a), (b), (c), 0, 0, 0)

// ---------------- unified pack/convert kernel (16B stores) ----------------
DEV void pack_pair_chunk8(const float* __restrict__ A, const float* __restrict__ B,
                          bf16_t* __restrict__ dst, size_t i) {
  size_t r = i >> 9, c = i & 511;
  const float4* pa = (const float4*)A + r * 1024 + c * 2;
  const float4* pb = (const float4*)B + r * 1024 + c * 2;
  float4 a0 = pa[0], a1 = pa[1];
  float4 b0 = pb[0], b1 = pb[1];
  bf16x8 oa = {(bf16_t)a0.x, (bf16_t)a0.y, (bf16_t)a0.z, (bf16_t)a0.w,
               (bf16_t)a1.x, (bf16_t)a1.y, (bf16_t)a1.z, (bf16_t)a1.w};
  bf16x8 ob = {(bf16_t)b0.x, (bf16_t)b0.y, (bf16_t)b0.z, (bf16_t)b0.w,
               (bf16_t)b1.x, (bf16_t)b1.y, (bf16_t)b1.z, (bf16_t)b1.w};
  ((bf16x8*)dst)[r * 1024 + c]       = oa;
  ((bf16x8*)dst)[r * 1024 + 512 + c] = ob;
}

__global__ void k_pack_all(const float* __restrict__ hidden, const float* __restrict__ mu,
                           const float* __restrict__ Wq, const float* __restrict__ Wmq,
                           const float* __restrict__ Wk, const float* __restrict__ Wmk,
                           const float* __restrict__ Wv, const float* __restrict__ Wmv,
                           const float* __restrict__ Wo,
                           bf16_t* __restrict__ Xb, bf16_t* __restrict__ Wqkv,
                           bf16_t* __restrict__ Wob) {
  const size_t t0 = 2097152, t1 = 4194304, t2 = 4718592, t3 = 5242880, t4 = 7340032;
  size_t stride = (size_t)gridDim.x * blockDim.x;
  for (size_t i = (size_t)blockIdx.x * blockDim.x + threadIdx.x; i < t4; i += stride) {
    if (i < t0) {
      pack_pair_chunk8(hidden, mu, Xb, i);
    } else if (i < t1) {
      pack_pair_chunk8(Wq, Wmq, Wqkv, i - t0);
    } else if (i < t2) {
      pack_pair_chunk8(Wk, Wmk, Wqkv + (size_t)4096 * 8192, i - t1);
    } else if (i < t3) {
      pack_pair_chunk8(Wv, Wmv, Wqkv + (size_t)5120 * 8192, i - t2);
    } else {
      size_t j = i - t3;
      const float4* p = (const float4*)Wo + j * 2;
      float4 v0 = p[0], v1 = p[1];
      bf16x8 o = {(bf16_t)v0.x, (bf16_t)v0.y, (bf16_t)v0.z, (bf16_t)v0.w,
                  (bf16_t)v1.x, (bf16_t)v1.y, (bf16_t)v1.z, (bf16_t)v1.w};
      ((bf16x8*)Wob)[j] = o;
    }
  }
}

// ---------------- 256x256 bf16 GEMM (R14 schedule, measured best) ----------------
template<typename CT, int NSPLIT>
__global__ __launch_bounds__(512, 2) void k_gemm256(
    const bf16_t* __restrict__ A, const bf16_t* __restrict__ B,
    CT* __restrict__ C, int M, int N, int Kfull) {
  __shared__ __align__(16) char lds[131072];
  const int tid = threadIdx.x, lane = tid & 63, wid = tid >> 6;
  const int l15 = lane & 15, lhi = lane >> 4;
  const int wr = wid >> 2, wc = wid & 3;
  const int bid = blockIdx.x, nwg = gridDim.x;
  const int cpx = nwg >> 3;
  const int swz = (bid & 7) * cpx + (bid >> 3);
  const int nbm = M >> 8;
  const int tiles = nbm * (N >> 8);
  const int ks = (NSPLIT > 1) ? (swz / tiles) : 0;
  const int t  = (NSPLIT > 1) ? (swz % tiles) : swz;
  const int bm = t % nbm, bn = t / nbm;   // bm-fast
  const int Kloop = Kfull / NSPLIT;
  const int nkt = Kloop >> 6;

  const size_t rowK = (size_t)Kfull * 2;
  const size_t kbase = (size_t)ks * Kloop * 2;
  const int off0 = wid * 1024 + lane * 16, off1 = off0 + 8192;
  const int r0 = off0 >> 7, r1 = off1 >> 7;
  const int c0 = ((off0 >> 4) & 7) ^ (r0 & 7);
  const int c1 = ((off1 >> 4) & 7) ^ (r1 & 7);
  const char* sA0 = (const char*)A + ((size_t)bm * 256 + r0) * rowK + kbase + c0 * 16;
  const char* sA1 = (const char*)A + ((size_t)bm * 256 + r1) * rowK + kbase + c1 * 16;
  const char* sB0 = (const char*)B + ((size_t)bn * 256 + r0) * rowK + kbase + c0 * 16;
  const char* sB1 = (const char*)B + ((size_t)bn * 256 + r1) * rowK + kbase + c1 * 16;
  const size_t hst = (size_t)128 * rowK;

  enum { A0S = 0, A1S = 16384, A2S = 32768, A3S = 49152,
         B0S = 65536, B1S = 81920, B2S = 98304, B3S = 114688 };

#define STG(slot, pa, pb, off) do { \
    gload_lds16((pa) + (off), lds + (slot) + wid * 1024); \
    gload_lds16((pb) + (off), lds + (slot) + 8192 + wid * 1024); } while (0)

  const bf16_t* Ae = (const bf16_t*)(lds + A0S + wr * 16384);
  const bf16_t* Be = (const bf16_t*)(lds + B0S + (wc >> 1) * 16384);
  const bf16_t* Ao = (const bf16_t*)(lds + A2S + wr * 16384);
  const bf16_t* Bo = (const bf16_t*)(lds + B2S + (wc >> 1) * 16384);
  const int bro = (wc & 1) * 64;

  f32x4 acc[8][4] = {};
  bf16x8 a[4][2], b[4][2];
  const int xr = l15 & 7;
  const int ck0 = (lhi ^ xr) * 8;
  const int ck1 = ((4 + lhi) ^ xr) * 8;

#define RD_A(base, rb) do { _Pragma("unroll") \
    for (int mi = 0; mi < 4; ++mi) { \
      const int ro = ((rb) + mi * 16 + l15) * 64; \
      a[mi][0] = *(const bf16x8*)((base) + ro + ck0); \
      a[mi][1] = *(const bf16x8*)((base) + ro + ck1); } } while (0)
#define RD_B2(base, n0) do { _Pragma("unroll") \
    for (int n = (n0); n < (n0) + 2; ++n) { \
      const int ro = (bro + n * 16 + l15) * 64; \
      b[n][0] = *(const bf16x8*)((base) + ro + ck0); \
      b[n][1] = *(const bf16x8*)((base) + ro + ck1); } } while (0)
#define MM(qm, qn) do { _Pragma("unroll") \
    for (int mi = 0; mi < 4; ++mi) { _Pragma("unroll") \
      for (int ni = 0; ni < 2; ++ni) { \
        f32x4 t_ = acc[(qm) * 4 + mi][(qn) * 2 + ni]; \
        t_ = MFMA16(a[mi][0], b[(qn) * 2 + ni][0], t_); \
        t_ = MFMA16(a[mi][1], b[(qn) * 2 + ni][1], t_); \
        acc[(qm) * 4 + mi][(qn) * 2 + ni] = t_; } } } while (0)
#define PRIO_MM(qm, qn) do { __builtin_amdgcn_s_setprio(1); MM(qm, qn); \
    __builtin_amdgcn_s_setprio(0); } while (0)

  // prologue: tile0 (B0,B1,A0,A1 @ K-byte 0) + tile1 (B2,B3,A2 @ K-byte 128)
  STG(B0S, sB0, sB1, 0);
  STG(B1S, sB0, sB1, hst);
  STG(A0S, sA0, sA1, 0);
  STG(A1S, sA0, sA1, hst);
  STG(B2S, sB0, sB1, 128);
  STG(B3S, sB0, sB1, 128 + hst);
  STG(A2S, sA0, sA1, 128);
  asm volatile("s_waitcnt vmcnt(6)" ::: "memory");
  BARRIER();

  size_t g = 0;
  for (int ktp = 0; ktp < nkt / 2 - 1; ++ktp) {
    // ======== tile even ========
    RD_A(Ae, 0); RD_B2(Be, 0);
    STG(A3S, sA0, sA1, g + 128 + hst);
    BARRIER();
    STG(B0S, sB0, sB1, g + 256);
    RD_B2(Be, 2);
    PRIO_MM(0, 0);
    BARRIER();
    PRIO_MM(0, 1);
    BARRIER();
    RD_A(Ae, 64);
    STG(B1S, sB0, sB1, g + 256 + hst);
    BARRIER();
    PRIO_MM(1, 0);
    BARRIER();
    STG(A0S, sA0, sA1, g + 256);
    BARRIER();
    PRIO_MM(1, 1);
    asm volatile("s_waitcnt vmcnt(6)" ::: "memory");
    BARRIER();
    // ======== tile odd ========
    RD_A(Ao, 0); RD_B2(Bo, 0);
    STG(A1S, sA0, sA1, g + 256 + hst);
    BARRIER();
    STG(B2S, sB0, sB1, g + 384);
    RD_B2(Bo, 2);
    PRIO_MM(0, 0);
    BARRIER();
    PRIO_MM(0, 1);
    BARRIER();
    RD_A(Ao, 64);
    STG(B3S, sB0, sB1, g + 384 + hst);
    BARRIER();
    PRIO_MM(1, 0);
    BARRIER();
    STG(A2S, sA0, sA1, g + 384);
    BARRIER();
    PRIO_MM(1, 1);
    asm volatile("s_waitcnt vmcnt(6)" ::: "memory");
    BARRIER();
    g += 256;
  }
  // ======== tail tile nkt-2 ========
  RD_A(Ae, 0); RD_B2(Be, 0); RD_B2(Be, 2);
  STG(A3S, sA0, sA1, g + 128 + hst);
  BARRIER();
  PRIO_MM(0, 0);
  PRIO_MM(0, 1);
  RD_A(Ae, 64);
  PRIO_MM(1, 0);
  PRIO_MM(1, 1);
  asm volatile("s_waitcnt vmcnt(0)" ::: "memory");
  BARRIER();
  // ======== tail tile nkt-1 ========
  RD_A(Ao, 0); RD_B2(Bo, 0); RD_B2(Bo, 2);
  PRIO_MM(0, 0);
  PRIO_MM(0, 1);
  RD_A(Ao, 64);
  PRIO_MM(1, 0);
  PRIO_MM(1, 1);

  CT* Cp = C + (size_t)ks * M * N;
#pragma unroll
  for (int m = 0; m < 8; ++m) {
    const int row0 = bm * 256 + wr * 128 + m * 16 + 4 * lhi;
#pragma unroll
    for (int n = 0; n < 4; ++n) {
      const int col = bn * 256 + wc * 64 + n * 16 + l15;
#pragma unroll
      for (int i = 0; i < 4; ++i)
        Cp[(size_t)(row0 + i) * N + col] = (CT)acc[m][n][i];
    }
  }
#undef STG
#undef RD_A
#undef RD_B2
#undef MM
#undef PRIO_MM
}

// ---------------- RMSNorm + RoPE (vectorized bf16x2, half-wave per slot) ----------------
__global__ __launch_bounds__(256) void k_norm_rope(
    const bf16_t* __restrict__ qkvA, const bf16_t* __restrict__ qkvB,
    const int* __restrict__ pos,
    const float* __restrict__ qw, const float* __restrict__ kw,
    bf16_t* __restrict__ Q, bf16_t* __restrict__ Kk, bf16_t* __restrict__ V) {
  const int lane = threadIdx.x & 63, wid = threadIdx.x >> 6;
  const int l32 = lane & 31;
  const int gslot = blockIdx.x * 8 + wid * 2 + (lane >> 5);
  const int n = gslot / 48, slot = gslot % 48;
  const int d0 = 2 * l32;
  const bf16_t* rowA = qkvA + (size_t)n * 6144;
  const bf16_t* rowB = qkvB + (size_t)n * 6144;

  if (slot >= 40) {
    const int h2 = slot - 40;
    const int c = 5120 + h2 * 128 + d0;
    bf16x2 aL = *(const bf16x2*)(rowA + c),     bL = *(const bf16x2*)(rowB + c);
    bf16x2 aH = *(const bf16x2*)(rowA + c + 64), bH = *(const bf16x2*)(rowB + c + 64);
    bf16x2 oL = {(bf16_t)((float)aL[0] + (float)bL[0]), (bf16_t)((float)aL[1] + (float)bL[1])};
    bf16x2 oH = {(bf16_t)((float)aH[0] + (float)bH[0]), (bf16_t)((float)aH[1] + (float)bH[1])};
    bf16_t* dst = V + ((size_t)n * 8 + h2) * 128;
    *(bf16x2*)(dst + d0) = oL;
    *(bf16x2*)(dst + d0 + 64) = oH;
    return;
  }
  const bool isq = slot < 32;
  const int h = isq ? slot : slot - 32;
  const int c = (isq ? h * 128 : 4096 + h * 128) + d0;
  bf16x2 aL = *(const bf16x2*)(rowA + c),      bL = *(const bf16x2*)(rowB + c);
  bf16x2 aH = *(const bf16x2*)(rowA + c + 64), bH = *(const bf16x2*)(rowB + c + 64);
  float xL0 = (float)aL[0] + (float)bL[0], xL1 = (float)aL[1] + (float)bL[1];
  float xH0 = (float)aH[0] + (float)bH[0], xH1 = (float)aH[1] + (float)bH[1];
  float ss = xL0 * xL0 + xL1 * xL1 + xH0 * xH0 + xH1 * xH1;
#pragma unroll
  for (int m = 16; m; m >>= 1) ss += __shfl_xor(ss, m, 64);
  const float inv = rsqrtf(ss * (1.0f / 128.0f) + 1e-6f);
  const float* wgt = isq ? qw : kw;
  float yL0 = xL0 * inv * wgt[d0],      yL1 = xL1 * inv * wgt[d0 + 1];
  float yH0 = xH0 * inv * wgt[d0 + 64], yH1 = xH1 * inv * wgt[d0 + 65];
  const float p = (float)pos[n];
  const float ang0 = p * expf((float)d0 * -0.14391156608f);
  const float ang1 = p * expf((float)(d0 + 1) * -0.14391156608f);
  float s0, c0f, s1, c1f;
  sincosf(ang0, &s0, &c0f);
  sincosf(ang1, &s1, &c1f);
  bf16x2 oL = {(bf16_t)(yL0 * c0f - yH0 * s0), (bf16_t)(yL1 * c1f - yH1 * s1)};
  bf16x2 oH = {(bf16_t)(yH0 * c0f + yL0 * s0), (bf16_t)(yH1 * c1f + yL1 * s1)};
  bf16_t* dst = isq ? (Q + ((size_t)n * 32 + h) * 128) : (Kk + ((size_t)n * 8 + h) * 128);
  *(bf16x2*)(dst + d0) = oL;
  *(bf16x2*)(dst + d0 + 64) = oH;
}

// ---------------- V transpose: V[4096][8][128] -> Vt[s][kvh][d][1024] ----------------
__global__ __launch_bounds__(256) void k_vt(const bf16_t* __restrict__ V,
                                            bf16_t* __restrict__ Vt) {
  __shared__ bf16_t T[64][136];
  const int blk = blockIdx.x;
  const int tt = blk & 15, kvh = (blk >> 4) & 7, s = blk >> 7;
  const int tok0 = tt * 64;
  const int tid = threadIdx.x;
#pragma unroll
  for (int k = 0; k < 4; ++k) {
    const int item = tid + k * 256;
    const int tok = item >> 4, d0 = (item & 15) * 8;
    bf16x8 v = *(const bf16x8*)(V + ((size_t)(s * 1024 + tok0 + tok) * 8 + kvh) * 128 + d0);
    *(bf16x8*)(&T[tok][d0]) = v;
  }
  __syncthreads();
#pragma unroll
  for (int k = 0; k < 4; ++k) {
    const int item = tid + k * 256;
    const int d = item & 127, oct = item >> 7;
    bf16x8 o;
#pragma unroll
    for (int j = 0; j < 8; ++j) o[j] = T[oct * 8 + j][d];
    *(bf16x8*)(Vt + ((size_t)((s * 8 + kvh) * 128 + d)) * 1024 + tok0 + oct * 8) = o;
  }
}

// ---------------- causal GQA flash attention ----------------
__global__ __launch_bounds__(256, 2) void k_attn(
    const bf16_t* __restrict__ Q, const bf16_t* __restrict__ Kk,
    const bf16_t* __restrict__ Vt, bf16_t* __restrict__ O) {
  __shared__ __align__(16) bf16_t Ks[2][64 * 128];
  __shared__ __align__(16) bf16_t Ps[4][32 * 72];
  const int b = blockIdx.x;
  const int x = b & 7, y = b >> 3;
  const int h = x * 4 + ((y >> 3) & 3);
  const int qb = 7 - (y & 7);
  const int s = y >> 5;
  const int kvh = h >> 2;
  const int tid = threadIdx.x, lane = tid & 63, wid = tid >> 6;
  const int l15 = lane & 15, lhi = lane >> 4;

  bf16x8 qf[2][4];
  {
    const int qrow = qb * 128 + wid * 32;
#pragma unroll
    for (int mt = 0; mt < 2; mt++) {
      const size_t base = ((size_t)(s * 1024 + qrow + mt * 16 + l15) * 32 + h) * 128;
#pragma unroll
      for (int kc = 0; kc < 4; kc++)
        qf[mt][kc] = *(const bf16x8*)(Q + base + kc * 32 + 8 * lhi);
    }
  }
  const bf16_t* Vtb = Vt + (size_t)((s * 8 + kvh) * 128) * 1024;

  f32x4 of[2][8] = {};
  float mx[2][4], li[2][4];
#pragma unroll
  for (int mt = 0; mt < 2; mt++)
#pragma unroll
    for (int i = 0; i < 4; i++) { mx[mt][i] = -1e30f; li[mt][i] = 0.f; }

  const int ktiles = (qb + 1) * 2;

  const int so = wid * 4096;
#define STAGE_K(kt_, buf_) do { _Pragma("unroll") \
    for (int c = 0; c < 4; ++c) { \
      const int o = so + c * 1024 + lane * 16; \
      const int krow = o >> 8; \
      const int cs = ((o >> 4) & 15) ^ (krow & 7); \
      const char* src = (const char*)(Kk + \
          ((size_t)(s * 1024 + (kt_) * 64 + krow) * 8 + kvh) * 128) + cs * 16; \
      gload_lds16(src, (char*)&Ks[buf_][0] + so + c * 1024); \
    } } while (0)

  STAGE_K(0, 0);
  asm volatile("s_waitcnt vmcnt(0)" ::: "memory");
  BARRIER();

  for (int kt = 0; kt < ktiles; kt++) {
    const int kv0 = kt * 64;
    const int buf = kt & 1;
    if (kt + 1 < ktiles) STAGE_K(kt + 1, buf ^ 1);

    f32x4 sf[2][4] = {};
#pragma unroll
    for (int kc = 0; kc < 4; kc++) {
      bf16x8 kf[4];
#pragma unroll
      for (int n = 0; n < 4; n++) {
        const int krow = n * 16 + l15;
        const int ci = (kc * 4 + lhi) ^ (krow & 7);
        kf[n] = *(const bf16x8*)(&Ks[buf][0] + krow * 128 + ci * 8);
      }
#pragma unroll
      for (int mt = 0; mt < 2; mt++)
#pragma unroll
        for (int n = 0; n < 4; n++)
          sf[mt][n] = MFMA16(qf[mt][kc], kf[n], sf[mt][n]);
    }

    const bool masked = (kt >= 2 * qb);
    const float scale = 0.08838834764831845f;
    float pv[2][4][4];
#pragma unroll
    for (int mt = 0; mt < 2; mt++) {
#pragma unroll
      for (int i = 0; i < 4; i++) {
        float rm = -1e30f;
#pragma unroll
        for (int n = 0; n < 4; n++) {
          float sv = sf[mt][n][i] * scale;
          if (masked) {
            const int kvg = kv0 + n * 16 + l15;
            const int qg = qb * 128 + wid * 32 + mt * 16 + 4 * lhi + i;
            if (kvg > qg) sv = -1e30f;
          }
          pv[mt][n][i] = sv;
          rm = fmaxf(rm, sv);
        }
#pragma unroll
        for (int mm = 1; mm < 16; mm <<= 1) rm = fmaxf(rm, __shfl_xor(rm, mm, 64));
        const float nm = fmaxf(mx[mt][i], rm);
        float ts = 0.f;
#pragma unroll
        for (int n = 0; n < 4; n++) {
          float e = __expf(pv[mt][n][i] - nm);
          pv[mt][n][i] = e;
          ts += e;
        }
#pragma unroll
        for (int mm = 1; mm < 16; mm <<= 1) ts += __shfl_xor(ts, mm, 64);
        const float al = __expf(mx[mt][i] - nm);
        li[mt][i] = li[mt][i] * al + ts;
        mx[mt][i] = nm;
#pragma unroll
        for (int n = 0; n < 8; n++) of[mt][n][i] *= al;
      }
    }

    bf16_t* myP = &Ps[wid][0];
#pragma unroll
    for (int mt = 0; mt < 2; mt++)
#pragma unroll
      for (int n = 0; n < 4; n++)
#pragma unroll
        for (int i = 0; i < 4; i++)
          myP[(mt * 16 + 4 * lhi + i) * 72 + n * 16 + l15] = (bf16_t)pv[mt][n][i];

#pragma unroll
    for (int kc = 0; kc < 2; kc++) {
      bf16x8 pf[2];
#pragma unroll
      for (int mt = 0; mt < 2; mt++)
        pf[mt] = *(const bf16x8*)(myP + (mt * 16 + l15) * 72 + kc * 32 + 8 * lhi);
#pragma unroll
      for (int n = 0; n < 8; n++) {
        const int d = n * 16 + l15;
        bf16x8 vf = *(const bf16x8*)(Vtb + (size_t)d * 1024 + kv0 + kc * 32 + 8 * lhi);
#pragma unroll
        for (int mt = 0; mt < 2; mt++)
          of[mt][n] = MFMA16(pf[mt], vf, of[mt][n]);
      }
    }

    if (kt + 1 < ktiles) {
      asm volatile("s_waitcnt vmcnt(0)" ::: "memory");
      BARRIER();
    }
  }
#undef STAGE_K

#pragma unroll
  for (int mt = 0; mt < 2; mt++) {
#pragma unroll
    for (int i = 0; i < 4; i++) {
      const float invl = 1.0f / li[mt][i];
      const int tokrow = qb * 128 + wid * 32 + mt * 16 + 4 * lhi + i;
      bf16_t* dst = O + (size_t)(s * 1024 + tokrow) * 4096 + h * 128;
#pragma unroll
      for (int n = 0; n < 8; n++)
        dst[n * 16 + l15] = (bf16_t)(of[mt][n][i] * invl);
    }
  }
}

// ---------------- launch ----------------
extern "C" void kernel_launch(void* const* d_in, const int* in_sizes, int n_in,
                              void* d_out, int out_size, void* d_ws, size_t ws_size,
                              hipStream_t stream) {
  const float* hidden = (const float*)d_in[0];
  const float* mu     = (const float*)d_in[1];
  const int*   pos    = (const int*)d_in[2];
  const float* Wq  = (const float*)d_in[3];
  const float* Wk  = (const float*)d_in[4];
  const float* Wv  = (const float*)d_in[5];
  const float* Wo  = (const float*)d_in[6];
  const float* Wmq = (const float*)d_in[7];
  const float* Wmk = (const float*)d_in[8];
  const float* Wmv = (const float*)d_in[9];
  const float* qw  = (const float*)d_in[10];
  const float* kw  = (const float*)d_in[11];
  float* out = (float*)d_out;
  char* ws = (char*)d_ws;

  if (ws_size < 301989888u) return;  // need 288 MiB

  bf16_t* Wqkv = (bf16_t*)(ws);                    // [6144][8192] bf16   0..96MiB
  bf16_t* Wob  = (bf16_t*)(ws + 100663296);        // [4096][4096] bf16   96..128MiB
  bf16_t* Xb   = (bf16_t*)(ws + 134217728);        // [4096][8192] bf16   128..192MiB
  bf16_t* Qb   = (bf16_t*)(ws + 134217728);        // aliases Xb (dead after GEMM1) 32MiB
  bf16_t* Kb   = (bf16_t*)(ws + 167772160);        // 8MiB
  bf16_t* Vb   = (bf16_t*)(ws + 176160768);        // 8MiB
  bf16_t* VtG  = (bf16_t*)(ws + 184549376);        // transposed V, 8MiB
  bf16_t* qkvA = (bf16_t*)(ws + 201326592);        // [4096][6144] bf16 partial ks=0 (48MiB)
  bf16_t* qkvB = (bf16_t*)(ws + 251658240);        // partial ks=1 (48MiB)
  bf16_t* Ob   = (bf16_t*)(ws + 201326592);        // aliases qkvA (dead after norm/rope) 32MiB

  k_pack_all<<<2048, 256, 0, stream>>>(hidden, mu, Wq, Wmq, Wk, Wmk, Wv, Wmv, Wo,
                                       Xb, Wqkv, Wob);
  k_gemm256<bf16_t, 2><<<768, 512, 0, stream>>>(Xb, Wqkv, qkvA, 4096, 6144, 8192);
  k_norm_rope<<<24576, 256, 0, stream>>>(qkvA, qkvB, pos, qw, kw, Qb, Kb, Vb);
  k_vt<<<512, 256, 0, stream>>>(Vb, VtG);
  k_attn<<<1024, 256, 0, stream>>>(Qb, Kb, VtG, Ob);
  k_gemm256<float, 1><<<256, 512, 0, stream>>>(Ob, Wob, out, 4096, 4096, 4096);
}